// Round 9
// baseline (243.514 us; speedup 1.0000x reference)
//
#include <hip/hip_runtime.h>
#include <hip/hip_bf16.h>

#define B_N 8192
#define D_K 256
#define BM  256
#define BN  32
#define JSPLIT 32
#define JSPAN (B_N / JSPLIT)     // 256
#define NTILE (JSPAN / BN)       // 8
#define NCLS 1024
#define INVT 14.285714285714286f
#define C1   20.60992907f        // INVT * log2(e)

typedef __bf16 bf16x8 __attribute__((ext_vector_type(8)));
typedef float  f32x16 __attribute__((ext_vector_type(16)));
typedef float  f32x4  __attribute__((ext_vector_type(4)));

#define AS1 __attribute__((address_space(1)))
#define AS3 __attribute__((address_space(3)))

__device__ __forceinline__ unsigned short f32_to_bf16_rne(float f) {
    unsigned int u = __float_as_uint(f);
    unsigned int r = (u + 0x7FFFu + ((u >> 16) & 1u)) >> 16;
    return (unsigned short)r;
}
__device__ __forceinline__ float bf16_to_f32(unsigned short u) {
    return __uint_as_float(((unsigned int)u) << 16);
}

// single tiny kernel replaces two hipMemsetAsync dispatches
__global__ void zero_kernel(float* __restrict__ out, int* __restrict__ hist) {
    int g = blockIdx.x * 256 + threadIdx.x;
    if (g < NCLS) hist[g] = 0;
    if (g == 0) out[0] = 0.0f;
}

// grid 2048 x 256: one wave per row. float4 loads, shfl reduce, bf16 store,
// label histogram + exact self = ||en_i||^2 (post-rounding).
__global__ void norm_kernel(const float* __restrict__ emb,
                            const int* __restrict__ labels,
                            unsigned short* __restrict__ en,
                            int* __restrict__ hist,
                            float* __restrict__ self_arr) {
    const int t = threadIdx.x;
    const int w = t >> 6, l = t & 63;
    const int row = blockIdx.x * 4 + w;
    f32x4 x = *reinterpret_cast<const f32x4*>(emb + (size_t)row * D_K + l * 4);
    float ss = x[0]*x[0] + x[1]*x[1] + x[2]*x[2] + x[3]*x[3];
    #pragma unroll
    for (int m = 1; m < 64; m <<= 1) ss += __shfl_xor(ss, m, 64);
    float sc = 1.0f / fmaxf(sqrtf(ss), 1e-12f);
    ushort4 o;
    o.x = f32_to_bf16_rne(x[0] * sc); o.y = f32_to_bf16_rne(x[1] * sc);
    o.z = f32_to_bf16_rne(x[2] * sc); o.w = f32_to_bf16_rne(x[3] * sc);
    *reinterpret_cast<ushort4*>(en + (size_t)row * D_K + l * 4) = o;
    float y0 = bf16_to_f32(o.x), y1 = bf16_to_f32(o.y),
          y2 = bf16_to_f32(o.z), y3 = bf16_to_f32(o.w);
    float s2 = y0*y0 + y1*y1 + y2*y2 + y3*y3;
    #pragma unroll
    for (int m = 1; m < 64; m <<= 1) s2 += __shfl_xor(s2, m, 64);
    if (l == 0) {
        self_arr[row] = s2;
        atomicAdd(&hist[labels[row]], 1);
    }
}

// BM=256 (wave w owns 64 i-rows as two 32-row MFMA chains sharing each
// A-read), BN=32 j-tiles, 2-buffer LDS (33 KB) -> 4 blocks/CU via JSPLIT=32
// (grid 1024). XCD swizzle: each XCD owns 4 itiles (512 KB, L2-resident)
// x all 32 jsplits.
__launch_bounds__(256, 4)
__global__ void loss_kernel(const unsigned short* __restrict__ en,
                            const int* __restrict__ labels,
                            float* __restrict__ s_part,
                            float* __restrict__ ps_part) {
    __shared__ __align__(16) unsigned short Bls[2][BN * D_K];  // 2 x 16 KB
    __shared__ __align__(16) int Lab_s[JSPAN];                 // 1 KB

    const int t  = threadIdx.x;
    const int l  = t & 63;
    const int w  = t >> 6;
    const int ir = l & 31;
    const int h  = l >> 5;

    // itile-major XCD swizzle: xcd owns itiles [4*xcd, 4*xcd+4), all jsplits
    const int b      = blockIdx.x;
    const int xcd    = b & 7;
    const int local  = b >> 3;               // [0,128)
    const int itile  = xcd * 4 + (local & 3);
    const int jsplit = local >> 2;           // [0,32)
    const int ibase  = itile * BM;
    const int j0     = jsplit * JSPAN;

    // resident i-side fragments: two 32-row chains, 16 ks-slices each
    bf16x8 bi0[16], bi1[16];
    {
        const unsigned short* ap0 =
            en + (size_t)(ibase + w * 64 + ir) * D_K + h * 8;
        const unsigned short* ap1 = ap0 + 32 * D_K;
        #pragma unroll
        for (int ks = 0; ks < 16; ++ks) {
            bi0[ks] = *reinterpret_cast<const bf16x8*>(ap0 + ks * 16);
            bi1[ks] = *reinterpret_cast<const bf16x8*>(ap1 + ks * 16);
        }
    }
    const int li0 = labels[ibase + w * 64 + ir];
    const int li1 = labels[ibase + w * 64 + 32 + ir];

    // hoisted staging addresses (srcm rd-invariant: rd steps rows by 8)
    const int srcm = (t & 31) ^ ((t >> 5) & 7);
    const unsigned short* gb =
        en + (size_t)(j0 + (t >> 5)) * D_K + srcm * 8;
    const char* abase0 = (const char*)Bls[0] + (size_t)ir * 512;
    const char* abase1 = (const char*)Bls[1] + (size_t)ir * 512;
    const int xr = (ir & 7) << 4;

    float sA0 = 0.f, sA1 = 0.f, sB0 = 0.f, sB1 = 0.f;
    float pA0 = 0.f, pA1 = 0.f, pB0 = 0.f, pB1 = 0.f;

#define STAGE(bufp, itv)                                                     \
    {                                                                        \
        const unsigned short* gsrc = gb + (size_t)(itv) * (BN * D_K);        \
        char* ldst = (char*)(bufp) + t * 16;                                 \
        _Pragma("unroll")                                                    \
        for (int rd = 0; rd < 4; ++rd)                                       \
            __builtin_amdgcn_global_load_lds(                                \
                (const AS1 void*)(gsrc + rd * 2048),                         \
                (AS3 void*)(ldst + rd * 4096), 16, 0, 0);                    \
    }

#define TILE_COMPUTE(arow_b, itv)                                            \
    {                                                                        \
        int ljv[16];                                                         \
        {                                                                    \
            const int lb = (itv) * BN + h * 4;                               \
            *(int4*)&ljv[0]  = *(const int4*)&Lab_s[lb];                     \
            *(int4*)&ljv[4]  = *(const int4*)&Lab_s[lb + 8];                 \
            *(int4*)&ljv[8]  = *(const int4*)&Lab_s[lb + 16];                \
            *(int4*)&ljv[12] = *(const int4*)&Lab_s[lb + 24];                \
        }                                                                    \
        f32x16 a0, a1;                                                       \
        _Pragma("unroll")                                                    \
        for (int q = 0; q < 16; ++q) { a0[q] = 0.0f; a1[q] = 0.0f; }         \
        __builtin_amdgcn_s_setprio(1);                                       \
        _Pragma("unroll")                                                    \
        for (int ks = 0; ks < 16; ++ks) {                                    \
            const bf16x8 af = *reinterpret_cast<const bf16x8*>(              \
                (arow_b) + ((((ks << 1) | h) << 4) ^ xr));                   \
            a0 = __builtin_amdgcn_mfma_f32_32x32x16_bf16(af, bi0[ks], a0,    \
                                                         0, 0, 0);           \
            a1 = __builtin_amdgcn_mfma_f32_32x32x16_bf16(af, bi1[ks], a1,    \
                                                         0, 0, 0);           \
        }                                                                    \
        __builtin_amdgcn_s_setprio(0);                                       \
        _Pragma("unroll")                                                    \
        for (int q = 0; q < 16; ++q) {                                       \
            float d0 = a0[q], d1 = a1[q];                                    \
            float e0 = __builtin_amdgcn_exp2f(fmaf(d0, C1, -C1));            \
            float e1 = __builtin_amdgcn_exp2f(fmaf(d1, C1, -C1));            \
            if (q & 1) {                                                     \
                sA1 += e0; pA1 += (ljv[q] == li0) ? d0 : 0.0f;               \
                sB1 += e1; pB1 += (ljv[q] == li1) ? d1 : 0.0f;               \
            } else {                                                         \
                sA0 += e0; pA0 += (ljv[q] == li0) ? d0 : 0.0f;               \
                sB0 += e1; pB0 += (ljv[q] == li1) ? d1 : 0.0f;               \
            }                                                                \
        }                                                                    \
    }

    // prologue: stage tile 0 + all j-labels of this span
    STAGE(Bls[0], 0);
    Lab_s[t & (JSPAN - 1)] = labels[j0 + (t & (JSPAN - 1))];
    __syncthreads();

    for (int it = 0; it < NTILE; it += 2) {
        if (it + 1 < NTILE) STAGE(Bls[1], it + 1);
        TILE_COMPUTE(abase0, it);
        __syncthreads();
        if (it + 2 < NTILE) STAGE(Bls[0], it + 2);
        TILE_COMPUTE(abase1, it + 1);
        __syncthreads();
    }
#undef STAGE
#undef TILE_COMPUTE

    // chains own distinct i-rows: reduce halves, write per-split partials
    float sA = sA0 + sA1, pA = pA0 + pA1;
    float sB = sB0 + sB1, pB = pB0 + pB1;
    sA += __shfl_xor(sA, 32, 64);  pA += __shfl_xor(pA, 32, 64);
    sB += __shfl_xor(sB, 32, 64);  pB += __shfl_xor(pB, 32, 64);
    if (h == 0) {
        const size_t base = (size_t)jsplit * B_N + ibase + w * 64 + ir;
        s_part[base]       = sA;
        ps_part[base]      = pA;
        s_part[base + 32]  = sB;
        ps_part[base + 32] = pB;
    }
}

// grid 32 x 256: one thread per row i. Sums the 32 per-split partials
// (coalesced), subtracts exact self, applies loss formula, block-reduces.
__global__ void final_kernel(const int* __restrict__ labels,
                             const float* __restrict__ s_part,
                             const float* __restrict__ ps_part,
                             const float* __restrict__ self_arr,
                             const int* __restrict__ hist,
                             float* __restrict__ out) {
    const int t = threadIdx.x;
    const int i = blockIdx.x * 256 + t;
    float s = 0.f, ps = 0.f;
    #pragma unroll 8
    for (int k = 0; k < JSPLIT; ++k) {
        s  += s_part[(size_t)k * B_N + i];
        ps += ps_part[(size_t)k * B_N + i];
    }
    ps -= self_arr[i];
    int pc = hist[labels[i]] - 1;
    float loss = (pc > 0) ? (INVT + logf(s)) - ps * INVT / (float)pc : 0.0f;
    #pragma unroll
    for (int m = 1; m < 64; m <<= 1) loss += __shfl_xor(loss, m, 64);
    __shared__ float part[4];
    if ((t & 63) == 0) part[t >> 6] = loss;
    __syncthreads();
    if (t == 0)
        atomicAdd(out, (part[0] + part[1] + part[2] + part[3]) * (1.0f / B_N));
}

extern "C" void kernel_launch(void* const* d_in, const int* in_sizes, int n_in,
                              void* d_out, int out_size, void* d_ws, size_t ws_size,
                              hipStream_t stream) {
    const float* emb    = (const float*)d_in[0];
    const int*   labels = (const int*)d_in[1];
    float*       out    = (float*)d_out;

    unsigned short* en = (unsigned short*)d_ws;                     // 4 MB
    float* s_part  = (float*)((char*)d_ws + (size_t)B_N * D_K * 2); // 1 MB
    float* ps_part = s_part + (size_t)JSPLIT * B_N;                 // 1 MB
    int*   hist    = (int*)(ps_part + (size_t)JSPLIT * B_N);        // 4 KB
    float* self_arr = (float*)(hist + NCLS);                        // 32 KB

    hipLaunchKernelGGL(zero_kernel, dim3(4), dim3(256), 0, stream, out, hist);
    hipLaunchKernelGGL(norm_kernel, dim3(B_N / 4), dim3(256), 0, stream,
                       emb, labels, en, hist, self_arr);
    hipLaunchKernelGGL(loss_kernel, dim3((B_N / BM) * JSPLIT), dim3(256), 0,
                       stream, en, labels, s_part, ps_part);
    hipLaunchKernelGGL(final_kernel, dim3(B_N / 256), dim3(256), 0, stream,
                       labels, s_part, ps_part, self_arr, hist, out);
}

// Round 10
// 106.419 us; speedup vs baseline: 2.2882x; 2.2882x over previous
//
#include <hip/hip_runtime.h>
#include <hip/hip_bf16.h>

#define B_N 8192
#define D_K 256
#define BM  128
#define BN  32
#define JSPLIT 16
#define JSPAN (B_N / JSPLIT)     // 512
#define NTILE (JSPAN / BN)       // 16
#define NCLS 1024
#define INVT 14.285714285714286f
#define C1   20.60992907f        // INVT * log2(e)

typedef __bf16 bf16x8 __attribute__((ext_vector_type(8)));
typedef float  f32x16 __attribute__((ext_vector_type(16)));
typedef float  f32x4  __attribute__((ext_vector_type(4)));

#define AS1 __attribute__((address_space(1)))
#define AS3 __attribute__((address_space(3)))

__device__ __forceinline__ unsigned short f32_to_bf16_rne(float f) {
    unsigned int u = __float_as_uint(f);
    unsigned int r = (u + 0x7FFFu + ((u >> 16) & 1u)) >> 16;
    return (unsigned short)r;
}
__device__ __forceinline__ float bf16_to_f32(unsigned short u) {
    return __uint_as_float(((unsigned int)u) << 16);
}

__global__ void zero_kernel(float* __restrict__ out, int* __restrict__ hist) {
    int g = blockIdx.x * 256 + threadIdx.x;
    if (g < NCLS) hist[g] = 0;
    if (g == 0) out[0] = 0.0f;
}

// grid 2048 x 256: one wave per row. float4 loads, shfl reduce, bf16 store,
// label histogram + exact self = ||en_i||^2 (post-rounding).
__global__ void norm_kernel(const float* __restrict__ emb,
                            const int* __restrict__ labels,
                            unsigned short* __restrict__ en,
                            int* __restrict__ hist,
                            float* __restrict__ self_arr) {
    const int t = threadIdx.x;
    const int w = t >> 6, l = t & 63;
    const int row = blockIdx.x * 4 + w;
    f32x4 x = *reinterpret_cast<const f32x4*>(emb + (size_t)row * D_K + l * 4);
    float ss = x[0]*x[0] + x[1]*x[1] + x[2]*x[2] + x[3]*x[3];
    #pragma unroll
    for (int m = 1; m < 64; m <<= 1) ss += __shfl_xor(ss, m, 64);
    float sc = 1.0f / fmaxf(sqrtf(ss), 1e-12f);
    ushort4 o;
    o.x = f32_to_bf16_rne(x[0] * sc); o.y = f32_to_bf16_rne(x[1] * sc);
    o.z = f32_to_bf16_rne(x[2] * sc); o.w = f32_to_bf16_rne(x[3] * sc);
    *reinterpret_cast<ushort4*>(en + (size_t)row * D_K + l * 4) = o;
    float y0 = bf16_to_f32(o.x), y1 = bf16_to_f32(o.y),
          y2 = bf16_to_f32(o.z), y3 = bf16_to_f32(o.w);
    float s2 = y0*y0 + y1*y1 + y2*y2 + y3*y3;
    #pragma unroll
    for (int m = 1; m < 64; m <<= 1) s2 += __shfl_xor(s2, m, 64);
    if (l == 0) {
        self_arr[row] = s2;
        atomicAdd(&hist[labels[row]], 1);
    }
}

// BM=128: wave w owns 32 i-rows resident in 64 VGPR (single bi set -- fits
// ~115 regs so real occupancy is 4 waves/SIMD). BN=32 j-tiles, 2-buffer LDS
// (34 KB -> LDS cap 4 blocks/CU). Grid 1024 = 4/CU. XCD swizzle: each XCD
// owns 8 itiles (512 KB, L2-resident) x all 16 jsplits.
__launch_bounds__(256, 2)
__global__ void loss_kernel(const unsigned short* __restrict__ en,
                            const int* __restrict__ labels,
                            float* __restrict__ s_part,
                            float* __restrict__ ps_part) {
    __shared__ __align__(16) unsigned short Bls[2][BN * D_K];  // 2 x 16 KB
    __shared__ __align__(16) int Lab_s[JSPAN];                 // 2 KB

    const int t  = threadIdx.x;
    const int l  = t & 63;
    const int w  = t >> 6;
    const int ir = l & 31;
    const int h  = l >> 5;

    // itile-major XCD swizzle: xcd owns itiles [8*xcd, 8*xcd+8), all jsplits
    const int b      = blockIdx.x;
    const int xcd    = b & 7;
    const int local  = b >> 3;               // [0,128)
    const int itile  = xcd * 8 + (local & 7);
    const int jsplit = local >> 3;           // [0,16)
    const int ibase  = itile * BM;
    const int j0     = jsplit * JSPAN;

    // resident i-side fragments: one 32-row chain, 16 ks-slices, 64 VGPR
    bf16x8 bi[16];
    {
        const unsigned short* ap =
            en + (size_t)(ibase + w * 32 + ir) * D_K + h * 8;
        #pragma unroll
        for (int ks = 0; ks < 16; ++ks)
            bi[ks] = *reinterpret_cast<const bf16x8*>(ap + ks * 16);
    }
    const int li = labels[ibase + w * 32 + ir];

    // hoisted staging addresses (srcm rd-invariant: rd steps rows by 8)
    const int srcm = (t & 31) ^ ((t >> 5) & 7);
    const unsigned short* gb =
        en + (size_t)(j0 + (t >> 5)) * D_K + srcm * 8;
    const char* abase0 = (const char*)Bls[0] + (size_t)ir * 512;
    const char* abase1 = (const char*)Bls[1] + (size_t)ir * 512;
    const int xr = (ir & 7) << 4;

    float s0 = 0.f, s1 = 0.f, ps0 = 0.f, ps1 = 0.f;

#define STAGE(bufp, itv)                                                     \
    {                                                                        \
        const unsigned short* gsrc = gb + (size_t)(itv) * (BN * D_K);        \
        char* ldst = (char*)(bufp) + t * 16;                                 \
        _Pragma("unroll")                                                    \
        for (int rd = 0; rd < 4; ++rd)                                       \
            __builtin_amdgcn_global_load_lds(                                \
                (const AS1 void*)(gsrc + rd * 2048),                         \
                (AS3 void*)(ldst + rd * 4096), 16, 0, 0);                    \
    }

#define TILE_COMPUTE(arow_b, itv)                                            \
    {                                                                        \
        int ljv[16];                                                         \
        {                                                                    \
            const int lb = (itv) * BN + h * 4;                               \
            *(int4*)&ljv[0]  = *(const int4*)&Lab_s[lb];                     \
            *(int4*)&ljv[4]  = *(const int4*)&Lab_s[lb + 8];                 \
            *(int4*)&ljv[8]  = *(const int4*)&Lab_s[lb + 16];                \
            *(int4*)&ljv[12] = *(const int4*)&Lab_s[lb + 24];                \
        }                                                                    \
        f32x16 acc;                                                          \
        _Pragma("unroll")                                                    \
        for (int q = 0; q < 16; ++q) acc[q] = 0.0f;                          \
        __builtin_amdgcn_s_setprio(1);                                       \
        _Pragma("unroll")                                                    \
        for (int ks = 0; ks < 16; ++ks) {                                    \
            const bf16x8 af = *reinterpret_cast<const bf16x8*>(              \
                (arow_b) + ((((ks << 1) | h) << 4) ^ xr));                   \
            acc = __builtin_amdgcn_mfma_f32_32x32x16_bf16(af, bi[ks], acc,   \
                                                          0, 0, 0);          \
        }                                                                    \
        __builtin_amdgcn_s_setprio(0);                                       \
        _Pragma("unroll")                                                    \
        for (int q = 0; q < 16; ++q) {                                       \
            float dot = acc[q];                                              \
            float e = __builtin_amdgcn_exp2f(fmaf(dot, C1, -C1));            \
            if (q & 1) { s1 += e; ps1 += (ljv[q] == li) ? dot : 0.0f; }      \
            else       { s0 += e; ps0 += (ljv[q] == li) ? dot : 0.0f; }      \
        }                                                                    \
    }

    // prologue: stage tile 0 + all j-labels of this span
    STAGE(Bls[0], 0);
    Lab_s[t]       = labels[j0 + t];
    Lab_s[t + 256] = labels[j0 + t + 256];
    __syncthreads();

    for (int it = 0; it < NTILE; it += 2) {
        if (it + 1 < NTILE) STAGE(Bls[1], it + 1);
        TILE_COMPUTE(abase0, it);
        __syncthreads();
        if (it + 2 < NTILE) STAGE(Bls[0], it + 2);
        TILE_COMPUTE(abase1, it + 1);
        __syncthreads();
    }
#undef STAGE
#undef TILE_COMPUTE

    // each wave owns distinct i-rows: halve-reduce, write per-split partials
    float s_acc  = s0 + s1;
    float ps_acc = ps0 + ps1;
    s_acc  += __shfl_xor(s_acc, 32, 64);
    ps_acc += __shfl_xor(ps_acc, 32, 64);
    if (h == 0) {
        const size_t base = (size_t)jsplit * B_N + ibase + w * 32 + ir;
        s_part[base]  = s_acc;
        ps_part[base] = ps_acc;
    }
}

// grid 32 x 256: one thread per row i. Sums the 16 per-split partials
// (coalesced), subtracts exact self, applies loss formula, block-reduces.
__global__ void final_kernel(const int* __restrict__ labels,
                             const float* __restrict__ s_part,
                             const float* __restrict__ ps_part,
                             const float* __restrict__ self_arr,
                             const int* __restrict__ hist,
                             float* __restrict__ out) {
    const int t = threadIdx.x;
    const int i = blockIdx.x * 256 + t;
    float s = 0.f, ps = 0.f;
    #pragma unroll
    for (int k = 0; k < JSPLIT; ++k) {
        s  += s_part[(size_t)k * B_N + i];
        ps += ps_part[(size_t)k * B_N + i];
    }
    ps -= self_arr[i];
    int pc = hist[labels[i]] - 1;
    float loss = (pc > 0) ? (INVT + logf(s)) - ps * INVT / (float)pc : 0.0f;
    #pragma unroll
    for (int m = 1; m < 64; m <<= 1) loss += __shfl_xor(loss, m, 64);
    __shared__ float part[4];
    if ((t & 63) == 0) part[t >> 6] = loss;
    __syncthreads();
    if (t == 0)
        atomicAdd(out, (part[0] + part[1] + part[2] + part[3]) * (1.0f / B_N));
}

extern "C" void kernel_launch(void* const* d_in, const int* in_sizes, int n_in,
                              void* d_out, int out_size, void* d_ws, size_t ws_size,
                              hipStream_t stream) {
    const float* emb    = (const float*)d_in[0];
    const int*   labels = (const int*)d_in[1];
    float*       out    = (float*)d_out;

    unsigned short* en = (unsigned short*)d_ws;                     // 4 MB
    float* s_part  = (float*)((char*)d_ws + (size_t)B_N * D_K * 2); // 512 KB
    float* ps_part = s_part + (size_t)JSPLIT * B_N;                 // 512 KB
    int*   hist    = (int*)(ps_part + (size_t)JSPLIT * B_N);        // 4 KB
    float* self_arr = (float*)(hist + NCLS);                        // 32 KB

    hipLaunchKernelGGL(zero_kernel, dim3(4), dim3(256), 0, stream, out, hist);
    hipLaunchKernelGGL(norm_kernel, dim3(B_N / 4), dim3(256), 0, stream,
                       emb, labels, en, hist, self_arr);
    hipLaunchKernelGGL(loss_kernel, dim3((B_N / BM) * JSPLIT), dim3(256), 0,
                       stream, en, labels, s_part, ps_part);
    hipLaunchKernelGGL(final_kernel, dim3(B_N / 256), dim3(256), 0, stream,
                       labels, s_part, ps_part, self_arr, hist, out);
}